// Round 2
// baseline (412.604 us; speedup 1.0000x reference)
//
#include <hip/hip_runtime.h>

// ---------------------------------------------------------------------------
// Fused single-head causal attention (B=4, S=2048, D=1024), fp32 in/out.
// Pipeline: Wt transpose-cast -> q/k/v proj (bf16 MFMA) -> scores (causal
// tile-skip) -> row softmax (in-place P bf16) -> PV (causal K-limit) -> out.
// GEMM: 128x128 tile, BK=64, global_load_lds staging, XOR-swizzled LDS.
// ---------------------------------------------------------------------------

typedef __attribute__((ext_vector_type(8))) short bf16x8_t;   // 8 bf16 = 4 VGPR
typedef __attribute__((ext_vector_type(4))) float f32x4_t;    // MFMA acc

static __device__ __forceinline__ unsigned short f2b(float f) {
  union { float f; unsigned u; } c; c.f = f;
  unsigned u = c.u;
  u += 0x7fffu + ((u >> 16) & 1u);   // round-to-nearest-even
  return (unsigned short)(u >> 16);
}

static __device__ __forceinline__ void gload16(const void* g, const void* l) {
  __builtin_amdgcn_global_load_lds(
      (const __attribute__((address_space(1))) void*)g,
      (__attribute__((address_space(3))) void*)(void*)(unsigned short*)l,
      16, 0, 0);
}

// ---------------------------------------------------------------------------
// Transpose + cast: in [inRows][inCols] (f32 or bf16) -> out [inCols][inRows] bf16
// ---------------------------------------------------------------------------
template<bool IN_F32>
__global__ __launch_bounds__(256)
void transpose_cast(const void* __restrict__ in, unsigned short* __restrict__ out,
                    int inRows, int inCols, long sIn, long sOut)
{
  __shared__ unsigned short t[32][34];
  const int bx = blockIdx.x;   // col tile of input
  const int by = blockIdx.y;   // row tile of input
  const int bz = blockIdx.z;
  const int x = threadIdx.x;   // 0..31
  const int y = threadIdx.y;   // 0..7
  const float* inf = (const float*)in + (size_t)bz * sIn;
  const unsigned short* inb = (const unsigned short*)in + (size_t)bz * sIn;
  unsigned short* ob = out + (size_t)bz * sOut;
#pragma unroll
  for (int yy = y; yy < 32; yy += 8) {
    const int r = by * 32 + yy, c = bx * 32 + x;
    unsigned short v;
    if (IN_F32) v = f2b(inf[(size_t)r * inCols + c]);
    else        v = inb[(size_t)r * inCols + c];
    t[yy][x] = v;
  }
  __syncthreads();
#pragma unroll
  for (int yy = y; yy < 32; yy += 8) {
    const int r = bx * 32 + yy, c = by * 32 + x;  // out[r][c] = in[c][r]
    ob[(size_t)r * inRows + c] = t[x][yy];
  }
}

// ---------------------------------------------------------------------------
// 128x128-tile bf16 MFMA GEMM, BK=64:
//   C[m,n] = scale * sum_k A[m,k]*Bt[n,k] (+bias[n])
//   A: fp32 (reg-staged + converted) or bf16 (global_load_lds).
//   Bt: bf16 [N][K] via global_load_lds.  C: bf16 or f32.
//   CAUSAL_SKIP: skip tiles with bx > by (scores).
//   CAUSAL_KLIM: K limited to (by+1)*128 per M-tile row (PV).
// LDS tile [128][64] bf16 (128B rows); 16B chunk swizzle: chunk ^= row&7.
// global_load_lds writes LINEAR (wave base + lane*16), so the swizzle is
// applied to the per-lane GLOBAL source chunk; ds_read applies the same XOR.
// 4 waves (2x2), 64x64 out each, 4x4 frags of 16x16x32.
// ---------------------------------------------------------------------------
template<bool A_IS_F32, bool HAS_BIAS, bool OUT_BF16, bool CAUSAL_SKIP, bool CAUSAL_KLIM>
__global__ __launch_bounds__(256)
void gemm128(const void* __restrict__ Ap, const unsigned short* __restrict__ Bt,
             const float* __restrict__ bias, void* __restrict__ Cp,
             int K, int lda, int ldb, int ldc,
             long sA, long sB, long sC, float scale)
{
  const int bx = blockIdx.x, by = blockIdx.y, bz = blockIdx.z;
  if (CAUSAL_SKIP && bx > by) return;
  int kEnd = K;
  if (CAUSAL_KLIM) { const int kl = (by + 1) * 128; kEnd = kl < K ? kl : K; }

  __shared__ unsigned short As[128 * 64];  // 16 KB, 128B rows
  __shared__ unsigned short Bs[128 * 64];

  const int tid  = threadIdx.x;
  const int lane = tid & 63;
  const int wid  = tid >> 6;
  const int wr   = wid >> 1, wc = wid & 1;   // 2x2 wave grid, 64x64 each
  const int l15  = lane & 15, l4 = lane >> 4;

  const float*          Af = (const float*)Ap + (size_t)bz * sA;
  const unsigned short* Ab = (const unsigned short*)Ap + (size_t)bz * sA;
  const unsigned short* Bb = Bt + (size_t)bz * sB;

  // gload staging: wave wid covers rows [i*32 + wid*8, +8), lane l -> row+(l>>3), chunk l&7
  const int srow_l = lane >> 3;
  const int schk   = lane & 7;
  // f32 reg staging: thread t -> row i*32 + (t>>3), float-chunk t&7
  const int frow = tid >> 3;
  const int fchk = tid & 7;

  f32x4_t acc[4][4];
#pragma unroll
  for (int m = 0; m < 4; ++m)
#pragma unroll
    for (int n = 0; n < 4; ++n) acc[m][n] = (f32x4_t){0.f, 0.f, 0.f, 0.f};

  for (int k0 = 0; k0 < kEnd; k0 += 64) {
    // ---- stage A tile [128][64] ----
    if (A_IS_F32) {
#pragma unroll
      for (int i = 0; i < 4; ++i) {
        const int row = i * 32 + frow;
        const size_t gr = (size_t)(by * 128 + row);
        const float* src = Af + gr * lda + k0 + fchk * 8;
        const float4 x0 = *(const float4*)src;
        const float4 x1 = *(const float4*)(src + 4);
        union { unsigned short s[8]; uint4 v; } pk;
        pk.s[0] = f2b(x0.x); pk.s[1] = f2b(x0.y); pk.s[2] = f2b(x0.z); pk.s[3] = f2b(x0.w);
        pk.s[4] = f2b(x1.x); pk.s[5] = f2b(x1.y); pk.s[6] = f2b(x1.z); pk.s[7] = f2b(x1.w);
        const int c = fchk ^ (row & 7);
        *(uint4*)&As[row * 64 + c * 8] = pk.v;
      }
    } else {
#pragma unroll
      for (int i = 0; i < 4; ++i) {
        const int row = i * 32 + wid * 8 + srow_l;
        const size_t gr = (size_t)(by * 128 + row);
        const int g = schk ^ (row & 7);
        gload16(Ab + gr * lda + k0 + g * 8, &As[(i * 32 + wid * 8) * 64]);
      }
    }
    // ---- stage B tile [128][64] ----
#pragma unroll
    for (int i = 0; i < 4; ++i) {
      const int row = i * 32 + wid * 8 + srow_l;
      const size_t gn = (size_t)(bx * 128 + row);
      const int g = schk ^ (row & 7);
      gload16(Bb + gn * ldb + k0 + g * 8, &Bs[(i * 32 + wid * 8) * 64]);
    }
    __syncthreads();

#pragma unroll
    for (int kk = 0; kk < 2; ++kk) {
      bf16x8_t a[4], b[4];
#pragma unroll
      for (int m = 0; m < 4; ++m) {
        const int row = wr * 64 + m * 16 + l15;
        const int c = (kk * 4 + l4) ^ (row & 7);
        a[m] = *(const bf16x8_t*)&As[row * 64 + c * 8];
      }
#pragma unroll
      for (int n = 0; n < 4; ++n) {
        const int row = wc * 64 + n * 16 + l15;
        const int c = (kk * 4 + l4) ^ (row & 7);
        b[n] = *(const bf16x8_t*)&Bs[row * 64 + c * 8];
      }
#pragma unroll
      for (int m = 0; m < 4; ++m)
#pragma unroll
        for (int n = 0; n < 4; ++n)
          acc[m][n] = __builtin_amdgcn_mfma_f32_16x16x32_bf16(a[m], b[n], acc[m][n], 0, 0, 0);
    }
    __syncthreads();
  }

  // ---- epilogue: C/D layout col = lane&15, row = (lane>>4)*4 + j ----
  float*          Cf = (float*)Cp + (size_t)bz * sC;
  unsigned short* Cb = (unsigned short*)Cp + (size_t)bz * sC;
#pragma unroll
  for (int m = 0; m < 4; ++m)
#pragma unroll
    for (int n = 0; n < 4; ++n) {
      const int col = bx * 128 + wc * 64 + n * 16 + l15;
      const float bv = HAS_BIAS ? bias[col] : 0.f;
#pragma unroll
      for (int j = 0; j < 4; ++j) {
        const int row = by * 128 + wr * 64 + m * 16 + l4 * 4 + j;
        const float val = acc[m][n][j] * scale + bv;
        if (OUT_BF16) Cb[(size_t)row * ldc + col] = f2b(val);
        else          Cf[(size_t)row * ldc + col] = val;
      }
    }
}

// ---------------------------------------------------------------------------
// Causal row softmax, in-place: reads fp32 score row (stride 2048 f32),
// writes bf16 probs into the same bytes (row stride 4096 bf16 elems).
// All global reads complete before the first barrier -> no WAR hazard.
// ---------------------------------------------------------------------------
__global__ __launch_bounds__(256)
void softmax_rows(const float* __restrict__ S, unsigned short* __restrict__ P)
{
  const int row = blockIdx.x;          // 0..8191  (= b*2048 + q)
  const int q = row & 2047;
  const float* srow = S + (size_t)row * 2048;
  unsigned short* prow = P + (size_t)row * 4096;
  const int nvalid = q + 1;
  const int kend = ((q >> 7) + 1) << 7;   // round up to 128-tile boundary
  const int tid = threadIdx.x;
  const int wid = tid >> 6, lane = tid & 63;

  float v[8];
  float m = -1e30f;
#pragma unroll
  for (int i = 0; i < 8; ++i) {
    const int idx = tid + i * 256;
    v[i] = (idx < nvalid) ? srow[idx] : -1e30f;
    m = fmaxf(m, v[i]);
  }
#pragma unroll
  for (int off = 32; off > 0; off >>= 1) m = fmaxf(m, __shfl_xor(m, off));
  __shared__ float redm[4];
  __shared__ float reds[4];
  if (lane == 0) redm[wid] = m;
  __syncthreads();
  m = fmaxf(fmaxf(redm[0], redm[1]), fmaxf(redm[2], redm[3]));

  float s = 0.f;
  float e[8];
#pragma unroll
  for (int i = 0; i < 8; ++i) {
    const int idx = tid + i * 256;
    e[i] = (idx < nvalid) ? __expf(v[i] - m) : 0.f;
    s += e[i];
  }
#pragma unroll
  for (int off = 32; off > 0; off >>= 1) s += __shfl_xor(s, off);
  if (lane == 0) reds[wid] = s;
  __syncthreads();
  s = reds[0] + reds[1] + reds[2] + reds[3];
  const float inv = 1.f / s;
#pragma unroll
  for (int i = 0; i < 8; ++i) {
    const int idx = tid + i * 256;
    if (idx < kend) prow[idx] = f2b(e[i] * inv);
  }
}

// ---------------------------------------------------------------------------
extern "C" void kernel_launch(void* const* d_in, const int* in_sizes, int n_in,
                              void* d_out, int out_size, void* d_ws, size_t ws_size,
                              hipStream_t stream)
{
  const float* query = (const float*)d_in[0];
  const float* key   = (const float*)d_in[1];
  const float* value = (const float*)d_in[2];
  const float* Wq    = (const float*)d_in[3];
  const float* bq    = (const float*)d_in[4];
  const float* Wk    = (const float*)d_in[5];
  const float* bk    = (const float*)d_in[6];
  const float* Wv    = (const float*)d_in[7];
  const float* bv    = (const float*)d_in[8];
  const float* Wo    = (const float*)d_in[9];
  const float* bo    = (const float*)d_in[10];
  float* out = (float*)d_out;

  char* ws = (char*)d_ws;
  const size_t MB = 1024 * 1024;
  unsigned short* Wqt  = (unsigned short*)(ws + 0 * MB);    // 2 MB each
  unsigned short* Wkt  = (unsigned short*)(ws + 2 * MB);
  unsigned short* Wvt  = (unsigned short*)(ws + 4 * MB);
  unsigned short* Wot  = (unsigned short*)(ws + 6 * MB);
  unsigned short* qbuf = (unsigned short*)(ws + 8 * MB);    // 16 MB each
  unsigned short* kbuf = (unsigned short*)(ws + 24 * MB);
  unsigned short* vbuf = (unsigned short*)(ws + 40 * MB);
  unsigned short* vT   = (unsigned short*)(ws + 56 * MB);
  float*          Sraw = (float*)(ws + 72 * MB);            // 64 MB
  unsigned short* ctx  = (unsigned short*)(ws + 136 * MB);  // 16 MB

  const dim3 tb(32, 8);

  // weights -> B^T bf16
  transpose_cast<true><<<dim3(32, 32, 1), tb, 0, stream>>>(Wq, Wqt, 1024, 1024, 0, 0);
  transpose_cast<true><<<dim3(32, 32, 1), tb, 0, stream>>>(Wk, Wkt, 1024, 1024, 0, 0);
  transpose_cast<true><<<dim3(32, 32, 1), tb, 0, stream>>>(Wv, Wvt, 1024, 1024, 0, 0);
  transpose_cast<true><<<dim3(32, 32, 1), tb, 0, stream>>>(Wo, Wot, 1024, 1024, 0, 0);

  // projections: [8192,1024] x [1024,1024] + bias -> bf16
  gemm128<true, true, true, false, false><<<dim3(8, 64, 1), 256, 0, stream>>>(
      query, Wqt, bq, qbuf, 1024, 1024, 1024, 1024, 0, 0, 0, 1.f);
  gemm128<true, true, true, false, false><<<dim3(8, 64, 1), 256, 0, stream>>>(
      key, Wkt, bk, kbuf, 1024, 1024, 1024, 1024, 0, 0, 0, 1.f);
  gemm128<true, true, true, false, false><<<dim3(8, 64, 1), 256, 0, stream>>>(
      value, Wvt, bv, vbuf, 1024, 1024, 1024, 1024, 0, 0, 0, 1.f);

  // scores = q k^T / 32, causal tile-skip, fp32 out
  gemm128<false, false, false, true, false><<<dim3(16, 16, 4), 256, 0, stream>>>(
      qbuf, kbuf, nullptr, Sraw, 1024, 1024, 1024, 2048,
      2048L * 1024, 2048L * 1024, 2048L * 2048, 0.03125f);

  // v -> vT [B][D][S] bf16
  transpose_cast<false><<<dim3(32, 64, 4), tb, 0, stream>>>(
      vbuf, vT, 2048, 1024, 2048L * 1024, 2048L * 1024);

  // causal softmax, in-place P (bf16) over Sraw
  softmax_rows<<<8192, 256, 0, stream>>>(Sraw, (unsigned short*)Sraw);

  // O = P @ V  (A = P bf16 stride 4096, B^T = vT, causal K-limit)
  gemm128<false, false, true, false, true><<<dim3(8, 16, 4), 256, 0, stream>>>(
      (unsigned short*)Sraw, vT, nullptr, ctx, 2048, 4096, 2048, 1024,
      2048L * 4096, 1024L * 2048, 2048L * 1024, 1.f);

  // out = ctx @ Wo + bo  -> fp32 d_out
  gemm128<false, true, false, false, false><<<dim3(8, 64, 1), 256, 0, stream>>>(
      ctx, Wot, bo, out, 1024, 1024, 1024, 1024, 0, 0, 0, 1.f);
}

// Round 3
// 397.584 us; speedup vs baseline: 1.0378x; 1.0378x over previous
//
#include <hip/hip_runtime.h>

// ---------------------------------------------------------------------------
// Fused single-head causal attention (B=4, S=2048, D=1024), fp32 in/out.
// Pipeline: Wt transpose (fused x4) -> QKV proj (fused, z-indexed) -> vT
// transpose -> scores (packed triangular grid) -> softmax (in-place, vec)
// -> PV (causal K-limit) -> out proj.   7 dispatches.
// GEMM: 128x128 tile, BK=64, global_load_lds staging, XOR-swizzled LDS.
// ---------------------------------------------------------------------------

typedef __attribute__((ext_vector_type(8))) short bf16x8_t;   // 8 bf16 = 4 VGPR
typedef __attribute__((ext_vector_type(4))) float f32x4_t;    // MFMA acc

static __device__ __forceinline__ unsigned short f2b(float f) {
  union { float f; unsigned u; } c; c.f = f;
  unsigned u = c.u;
  u += 0x7fffu + ((u >> 16) & 1u);   // round-to-nearest-even
  return (unsigned short)(u >> 16);
}

static __device__ __forceinline__ void gload16(const void* g, const void* l) {
  __builtin_amdgcn_global_load_lds(
      (const __attribute__((address_space(1))) void*)g,
      (__attribute__((address_space(3))) void*)(void*)(unsigned short*)l,
      16, 0, 0);
}

// ---------------------------------------------------------------------------
// GEMM body: 128x128 tile, BK=64. C[m,n] = scale*sum_k A[m,k]*Bt[n,k] (+bias)
// A: fp32 (reg-staged+converted) or bf16 (global_load_lds). Bt: bf16 [N][K].
// LDS tile [128][64] bf16 (128B rows); 16B-chunk swizzle: chunk ^= row&7,
// applied to the GLOBAL source for gload_lds (linear LDS dest) and to the
// ds_read address — both-sides involution.
// 4 waves (2x2), 64x64 out each, 4x4 frags of 16x16x32 bf16 MFMA.
// ---------------------------------------------------------------------------
template<bool A_IS_F32, bool HAS_BIAS, bool OUT_BF16>
static __device__ __forceinline__
void gemm_body(const void* __restrict__ Ap, const unsigned short* __restrict__ Bt,
               const float* __restrict__ bias, void* __restrict__ Cp,
               int kEnd, int lda, int ldb, int ldc, float scale, int bx, int by)
{
  __shared__ unsigned short As[128 * 64];  // 16 KB
  __shared__ unsigned short Bs[128 * 64];  // 16 KB

  const int tid  = threadIdx.x;
  const int lane = tid & 63;
  const int wid  = tid >> 6;
  const int wr   = wid >> 1, wc = wid & 1;   // 2x2 wave grid, 64x64 each
  const int l15  = lane & 15, l4 = lane >> 4;

  const float*          Af = (const float*)Ap;
  const unsigned short* Ab = (const unsigned short*)Ap;

  const int srow_l = lane >> 3;   // gload: lane -> row within 8-row group
  const int schk   = lane & 7;    // gload: 16B chunk
  const int frow = tid >> 3;      // f32 staging: row within 32-row group
  const int fchk = tid & 7;       // f32 staging: 8-float chunk

  f32x4_t acc[4][4];
#pragma unroll
  for (int m = 0; m < 4; ++m)
#pragma unroll
    for (int n = 0; n < 4; ++n) acc[m][n] = (f32x4_t){0.f, 0.f, 0.f, 0.f};

  for (int k0 = 0; k0 < kEnd; k0 += 64) {
    // ---- stage A tile [128][64] ----
    if (A_IS_F32) {
#pragma unroll
      for (int i = 0; i < 4; ++i) {
        const int row = i * 32 + frow;
        const size_t gr = (size_t)(by * 128 + row);
        const float* src = Af + gr * lda + k0 + fchk * 8;
        const float4 x0 = *(const float4*)src;
        const float4 x1 = *(const float4*)(src + 4);
        union { unsigned short s[8]; uint4 v; } pk;
        pk.s[0] = f2b(x0.x); pk.s[1] = f2b(x0.y); pk.s[2] = f2b(x0.z); pk.s[3] = f2b(x0.w);
        pk.s[4] = f2b(x1.x); pk.s[5] = f2b(x1.y); pk.s[6] = f2b(x1.z); pk.s[7] = f2b(x1.w);
        const int c = fchk ^ (row & 7);
        *(uint4*)&As[row * 64 + c * 8] = pk.v;
      }
    } else {
#pragma unroll
      for (int i = 0; i < 4; ++i) {
        const int row = i * 32 + wid * 8 + srow_l;
        const size_t gr = (size_t)(by * 128 + row);
        const int g = schk ^ (row & 7);
        gload16(Ab + gr * lda + k0 + g * 8, &As[(i * 32 + wid * 8) * 64]);
      }
    }
    // ---- stage B tile [128][64] ----
#pragma unroll
    for (int i = 0; i < 4; ++i) {
      const int row = i * 32 + wid * 8 + srow_l;
      const size_t gn = (size_t)(bx * 128 + row);
      const int g = schk ^ (row & 7);
      gload16(Bt + gn * ldb + k0 + g * 8, &Bs[(i * 32 + wid * 8) * 64]);
    }
    __syncthreads();

#pragma unroll
    for (int kk = 0; kk < 2; ++kk) {
      bf16x8_t a[4], b[4];
#pragma unroll
      for (int m = 0; m < 4; ++m) {
        const int row = wr * 64 + m * 16 + l15;
        const int c = (kk * 4 + l4) ^ (row & 7);
        a[m] = *(const bf16x8_t*)&As[row * 64 + c * 8];
      }
#pragma unroll
      for (int n = 0; n < 4; ++n) {
        const int row = wc * 64 + n * 16 + l15;
        const int c = (kk * 4 + l4) ^ (row & 7);
        b[n] = *(const bf16x8_t*)&Bs[row * 64 + c * 8];
      }
#pragma unroll
      for (int m = 0; m < 4; ++m)
#pragma unroll
        for (int n = 0; n < 4; ++n)
          acc[m][n] = __builtin_amdgcn_mfma_f32_16x16x32_bf16(a[m], b[n], acc[m][n], 0, 0, 0);
    }
    __syncthreads();
  }

  // ---- epilogue: C/D layout col = lane&15, row = (lane>>4)*4 + j ----
  float*          Cf = (float*)Cp;
  unsigned short* Cb = (unsigned short*)Cp;
#pragma unroll
  for (int m = 0; m < 4; ++m)
#pragma unroll
    for (int n = 0; n < 4; ++n) {
      const int col = bx * 128 + wc * 64 + n * 16 + l15;
      const float bv = HAS_BIAS ? bias[col] : 0.f;
#pragma unroll
      for (int j = 0; j < 4; ++j) {
        const int row = by * 128 + wr * 64 + m * 16 + l4 * 4 + j;
        const float val = acc[m][n][j] * scale + bv;
        if (OUT_BF16) Cb[(size_t)row * ldc + col] = f2b(val);
        else          Cf[(size_t)row * ldc + col] = val;
      }
    }
}

// ---------------------------------------------------------------------------
// Fused QKV projection: z selects (input, weight, bias, output).
// grid (8, 64, 3) -> 1536 blocks (~6/CU vs 2/CU unfused).
// ---------------------------------------------------------------------------
__global__ __launch_bounds__(256)
void gemm_qkv(const float* __restrict__ q, const float* __restrict__ k,
              const float* __restrict__ v,
              const unsigned short* __restrict__ Wq,
              const unsigned short* __restrict__ Wk,
              const unsigned short* __restrict__ Wv,
              const float* __restrict__ bq, const float* __restrict__ bk,
              const float* __restrict__ bv,
              unsigned short* __restrict__ oq, unsigned short* __restrict__ ok,
              unsigned short* __restrict__ ov)
{
  const int z = blockIdx.z;
  const float* A = z == 0 ? q : (z == 1 ? k : v);
  const unsigned short* B = z == 0 ? Wq : (z == 1 ? Wk : Wv);
  const float* bias = z == 0 ? bq : (z == 1 ? bk : bv);
  unsigned short* C = z == 0 ? oq : (z == 1 ? ok : ov);
  gemm_body<true, true, true>(A, B, bias, C, 1024, 1024, 1024, 1024, 1.f,
                              blockIdx.x, blockIdx.y);
}

// ---------------------------------------------------------------------------
// Scores = q k^T / 32, packed triangular grid: t -> (bx<=by), 136 tiles/batch.
// ---------------------------------------------------------------------------
__global__ __launch_bounds__(256)
void gemm_scores(const unsigned short* __restrict__ Q,
                 const unsigned short* __restrict__ Kb, float* __restrict__ S)
{
  const int bz = blockIdx.z;
  const int t = blockIdx.x;
  int by = (int)((sqrtf(8.f * t + 1.f) - 1.f) * 0.5f);
  while ((by + 1) * (by + 2) / 2 <= t) ++by;
  while (by * (by + 1) / 2 > t) --by;
  const int bx = t - by * (by + 1) / 2;
  gemm_body<false, false, false>(Q + (size_t)bz * 2048 * 1024,
                                 Kb + (size_t)bz * 2048 * 1024, nullptr,
                                 S + (size_t)bz * 2048 * 2048,
                                 1024, 1024, 1024, 2048, 0.03125f, bx, by);
}

// ---------------------------------------------------------------------------
// O = P @ V: A = P bf16 (row stride 4096), Bt = vT, causal K-limit per by.
// ---------------------------------------------------------------------------
__global__ __launch_bounds__(256)
void gemm_pv(const unsigned short* __restrict__ P,
             const unsigned short* __restrict__ Vt, unsigned short* __restrict__ C)
{
  const int bz = blockIdx.z, bx = blockIdx.x, by = blockIdx.y;
  const int kEnd = (by + 1) * 128;
  gemm_body<false, false, true>(P + (size_t)bz * 2048 * 4096,
                                Vt + (size_t)bz * 1024 * 2048, nullptr,
                                C + (size_t)bz * 2048 * 1024,
                                kEnd, 4096, 2048, 1024, 1.f, bx, by);
}

// ---------------------------------------------------------------------------
// out = ctx @ Wo + bo -> fp32
// ---------------------------------------------------------------------------
__global__ __launch_bounds__(256)
void gemm_out(const unsigned short* __restrict__ ctx,
              const unsigned short* __restrict__ Wo,
              const float* __restrict__ bo, float* __restrict__ out)
{
  gemm_body<false, true, false>(ctx, Wo, bo, out, 1024, 1024, 1024, 1024, 1.f,
                                blockIdx.x, blockIdx.y);
}

// ---------------------------------------------------------------------------
// 4 weight transposes fused: z selects W. [1024][1024] f32 -> bf16 transposed.
// ---------------------------------------------------------------------------
__global__ __launch_bounds__(256)
void transpose4_w(const float* __restrict__ w0, const float* __restrict__ w1,
                  const float* __restrict__ w2, const float* __restrict__ w3,
                  unsigned short* __restrict__ o0, unsigned short* __restrict__ o1,
                  unsigned short* __restrict__ o2, unsigned short* __restrict__ o3)
{
  __shared__ unsigned short t[32][34];
  const int z = blockIdx.z;
  const float* in = z == 0 ? w0 : (z == 1 ? w1 : (z == 2 ? w2 : w3));
  unsigned short* out = z == 0 ? o0 : (z == 1 ? o1 : (z == 2 ? o2 : o3));
  const int bx = blockIdx.x, by = blockIdx.y;
  const int x = threadIdx.x, y = threadIdx.y;
#pragma unroll
  for (int yy = y; yy < 32; yy += 8)
    t[yy][x] = f2b(in[(size_t)(by * 32 + yy) * 1024 + bx * 32 + x]);
  __syncthreads();
#pragma unroll
  for (int yy = y; yy < 32; yy += 8)
    out[(size_t)(bx * 32 + yy) * 1024 + by * 32 + x] = t[x][yy];
}

// ---------------------------------------------------------------------------
// vbuf [B][S][D] bf16 -> vT [B][D][S] bf16
// ---------------------------------------------------------------------------
__global__ __launch_bounds__(256)
void transpose_v(const unsigned short* __restrict__ in, unsigned short* __restrict__ out)
{
  __shared__ unsigned short t[32][34];
  const int bx = blockIdx.x;   // col tile (D)
  const int by = blockIdx.y;   // row tile (S)
  const int bz = blockIdx.z;
  const int x = threadIdx.x, y = threadIdx.y;
  const unsigned short* inb = in + (size_t)bz * 2048 * 1024;
  unsigned short* ob = out + (size_t)bz * 1024 * 2048;
#pragma unroll
  for (int yy = y; yy < 32; yy += 8)
    t[yy][x] = inb[(size_t)(by * 32 + yy) * 1024 + bx * 32 + x];
  __syncthreads();
#pragma unroll
  for (int yy = y; yy < 32; yy += 8)
    ob[(size_t)(bx * 32 + yy) * 2048 + by * 32 + x] = t[x][yy];
}

// ---------------------------------------------------------------------------
// Causal row softmax, in-place, vectorized: float4 loads, uint4 bf16 stores.
// All global reads complete before the final barrier -> no WAR hazard.
// ---------------------------------------------------------------------------
__global__ __launch_bounds__(256)
void softmax_rows(const float* __restrict__ S, unsigned short* __restrict__ P)
{
  const int row = blockIdx.x;          // 0..8191  (= b*2048 + q)
  const int q = row & 2047;
  const float* srow = S + (size_t)row * 2048;
  unsigned short* prow = P + (size_t)row * 4096;
  const int nvalid = q + 1;
  const int kend = ((q >> 7) + 1) << 7;   // multiple of 128
  const int tid = threadIdx.x;
  const int wid = tid >> 6, lane = tid & 63;
  const int base = tid * 8;

  const float4 x0 = *(const float4*)(srow + base);
  const float4 x1 = *(const float4*)(srow + base + 4);
  float v[8] = {x0.x, x0.y, x0.z, x0.w, x1.x, x1.y, x1.z, x1.w};

  float m = -1e30f;
#pragma unroll
  for (int i = 0; i < 8; ++i) {
    if (base + i >= nvalid) v[i] = -1e30f;
    m = fmaxf(m, v[i]);
  }
#pragma unroll
  for (int off = 32; off > 0; off >>= 1) m = fmaxf(m, __shfl_xor(m, off));
  __shared__ float redm[4];
  __shared__ float reds[4];
  if (lane == 0) redm[wid] = m;
  __syncthreads();
  m = fmaxf(fmaxf(redm[0], redm[1]), fmaxf(redm[2], redm[3]));

  float s = 0.f;
  float e[8];
#pragma unroll
  for (int i = 0; i < 8; ++i) {
    e[i] = (base + i < nvalid) ? __expf(v[i] - m) : 0.f;
    s += e[i];
  }
#pragma unroll
  for (int off = 32; off > 0; off >>= 1) s += __shfl_xor(s, off);
  if (lane == 0) reds[wid] = s;
  __syncthreads();
  s = reds[0] + reds[1] + reds[2] + reds[3];
  const float inv = 1.f / s;

  if (base < kend) {
    union { unsigned u[4]; uint4 v4; } pk;
#pragma unroll
    for (int i = 0; i < 4; ++i) {
      const unsigned lo = f2b(e[2 * i] * inv);
      const unsigned hi = f2b(e[2 * i + 1] * inv);
      pk.u[i] = lo | (hi << 16);
    }
    *(uint4*)(prow + base) = pk.v4;
  }
}

// ---------------------------------------------------------------------------
extern "C" void kernel_launch(void* const* d_in, const int* in_sizes, int n_in,
                              void* d_out, int out_size, void* d_ws, size_t ws_size,
                              hipStream_t stream)
{
  const float* query = (const float*)d_in[0];
  const float* key   = (const float*)d_in[1];
  const float* value = (const float*)d_in[2];
  const float* Wq    = (const float*)d_in[3];
  const float* bq    = (const float*)d_in[4];
  const float* Wk    = (const float*)d_in[5];
  const float* bk    = (const float*)d_in[6];
  const float* Wv    = (const float*)d_in[7];
  const float* bv    = (const float*)d_in[8];
  const float* Wo    = (const float*)d_in[9];
  const float* bo    = (const float*)d_in[10];
  float* out = (float*)d_out;

  char* ws = (char*)d_ws;
  const size_t MB = 1024 * 1024;
  unsigned short* Wqt  = (unsigned short*)(ws + 0 * MB);    // 2 MB each
  unsigned short* Wkt  = (unsigned short*)(ws + 2 * MB);
  unsigned short* Wvt  = (unsigned short*)(ws + 4 * MB);
  unsigned short* Wot  = (unsigned short*)(ws + 6 * MB);
  unsigned short* qbuf = (unsigned short*)(ws + 8 * MB);    // 16 MB each
  unsigned short* kbuf = (unsigned short*)(ws + 24 * MB);
  unsigned short* vbuf = (unsigned short*)(ws + 40 * MB);
  unsigned short* vT   = (unsigned short*)(ws + 56 * MB);
  float*          Sraw = (float*)(ws + 72 * MB);            // 64 MB
  unsigned short* ctx  = (unsigned short*)(ws + 136 * MB);  // 16 MB

  // 1) weights -> B^T bf16 (fused x4)
  transpose4_w<<<dim3(32, 32, 4), dim3(32, 8), 0, stream>>>(
      Wq, Wk, Wv, Wo, Wqt, Wkt, Wvt, Wot);

  // 2) fused q/k/v projections: [8192,1024]x[1024,1024]+bias -> bf16
  gemm_qkv<<<dim3(8, 64, 3), 256, 0, stream>>>(
      query, key, value, Wqt, Wkt, Wvt, bq, bk, bv, qbuf, kbuf, vbuf);

  // 3) v -> vT [B][D][S]
  transpose_v<<<dim3(32, 64, 4), dim3(32, 8), 0, stream>>>(vbuf, vT);

  // 4) scores = q k^T / 32, packed triangular grid, fp32 out
  gemm_scores<<<dim3(136, 1, 4), 256, 0, stream>>>(qbuf, kbuf, Sraw);

  // 5) causal softmax, in-place P (bf16) over Sraw
  softmax_rows<<<8192, 256, 0, stream>>>(Sraw, (unsigned short*)Sraw);

  // 6) O = P @ V (causal K-limit)
  gemm_pv<<<dim3(8, 16, 4), 256, 0, stream>>>((unsigned short*)Sraw, vT, ctx);

  // 7) out = ctx @ Wo + bo -> fp32 d_out
  gemm_out<<<dim3(8, 64, 1), 256, 0, stream>>>(ctx, Wot, bo, out);
}

// Round 4
// 347.202 us; speedup vs baseline: 1.1884x; 1.1451x over previous
//
#include <hip/hip_runtime.h>

// ---------------------------------------------------------------------------
// Fused single-head causal attention (B=4, S=2048, D=1024), fp32 in/out.
// Pipeline: cast q/k/v -> W transpose (x4 fused) -> QKV proj (z-indexed,
// all-bf16, XCD-swizzled) -> vT transpose -> scores (packed triangular,
// XCD-swizzled) -> softmax (in-place) -> PV (causal K-limit) -> out proj.
// GEMM: 128x128 tile, BK=64, global_load_lds both operands, XOR-swizzled LDS.
// ---------------------------------------------------------------------------

typedef __attribute__((ext_vector_type(8))) short bf16x8_t;   // 8 bf16 = 4 VGPR
typedef __attribute__((ext_vector_type(4))) float f32x4_t;    // MFMA acc

static __device__ __forceinline__ unsigned short f2b(float f) {
  union { float f; unsigned u; } c; c.f = f;
  unsigned u = c.u;
  u += 0x7fffu + ((u >> 16) & 1u);   // round-to-nearest-even
  return (unsigned short)(u >> 16);
}

static __device__ __forceinline__ void gload16(const void* g, const void* l) {
  __builtin_amdgcn_global_load_lds(
      (const __attribute__((address_space(1))) void*)g,
      (__attribute__((address_space(3))) void*)(void*)(unsigned short*)l,
      16, 0, 0);
}

// ---------------------------------------------------------------------------
// Cast q,k,v fp32 -> bf16. grid (4096, 3), 8 elems/thread.
// ---------------------------------------------------------------------------
__global__ __launch_bounds__(256)
void cast3_bf16(const float* __restrict__ q, const float* __restrict__ k,
                const float* __restrict__ v,
                unsigned short* __restrict__ oq, unsigned short* __restrict__ ok,
                unsigned short* __restrict__ ov)
{
  const int z = blockIdx.z;
  const float* in = z == 0 ? q : (z == 1 ? k : v);
  unsigned short* out = z == 0 ? oq : (z == 1 ? ok : ov);
  const size_t base = ((size_t)blockIdx.x * 256 + threadIdx.x) * 8;
  const float4 x0 = *(const float4*)(in + base);
  const float4 x1 = *(const float4*)(in + base + 4);
  union { unsigned u[4]; uint4 v4; } pk;
  pk.u[0] = f2b(x0.x) | ((unsigned)f2b(x0.y) << 16);
  pk.u[1] = f2b(x0.z) | ((unsigned)f2b(x0.w) << 16);
  pk.u[2] = f2b(x1.x) | ((unsigned)f2b(x1.y) << 16);
  pk.u[3] = f2b(x1.z) | ((unsigned)f2b(x1.w) << 16);
  *(uint4*)(out + base) = pk.v4;
}

// ---------------------------------------------------------------------------
// GEMM body: 128x128 tile, BK=64, all-bf16 operands via global_load_lds.
// C[m,n] = scale*sum_k A[m,k]*Bt[n,k] (+bias[n]).  Bt: bf16 [N][K].
// LDS tile [128][64] bf16 (128B rows); 16B-chunk swizzle chunk^=row&7 applied
// to the GLOBAL source (linear LDS dest for gload_lds) and the ds_read addr.
// 4 waves (2x2), 64x64 out each, 4x4 frags of 16x16x32 bf16 MFMA.
// ---------------------------------------------------------------------------
template<bool HAS_BIAS, bool OUT_BF16>
static __device__ __forceinline__
void gemm_body(const unsigned short* __restrict__ Ab,
               const unsigned short* __restrict__ Bt,
               const float* __restrict__ bias, void* __restrict__ Cp,
               int kEnd, int lda, int ldb, int ldc, float scale, int bx, int by)
{
  __shared__ unsigned short As[128 * 64];  // 16 KB
  __shared__ unsigned short Bs[128 * 64];  // 16 KB

  const int tid  = threadIdx.x;
  const int lane = tid & 63;
  const int wid  = tid >> 6;
  const int wr   = wid >> 1, wc = wid & 1;   // 2x2 wave grid, 64x64 each
  const int l15  = lane & 15, l4 = lane >> 4;

  const int srow_l = lane >> 3;   // gload: lane -> row within 8-row group
  const int schk   = lane & 7;    // gload: 16B chunk

  f32x4_t acc[4][4];
#pragma unroll
  for (int m = 0; m < 4; ++m)
#pragma unroll
    for (int n = 0; n < 4; ++n) acc[m][n] = (f32x4_t){0.f, 0.f, 0.f, 0.f};

  for (int k0 = 0; k0 < kEnd; k0 += 64) {
    // ---- stage A tile [128][64] ----
#pragma unroll
    for (int i = 0; i < 4; ++i) {
      const int row = i * 32 + wid * 8 + srow_l;
      const size_t gr = (size_t)(by * 128 + row);
      const int g = schk ^ (row & 7);
      gload16(Ab + gr * lda + k0 + g * 8, &As[(i * 32 + wid * 8) * 64]);
    }
    // ---- stage B tile [128][64] ----
#pragma unroll
    for (int i = 0; i < 4; ++i) {
      const int row = i * 32 + wid * 8 + srow_l;
      const size_t gn = (size_t)(bx * 128 + row);
      const int g = schk ^ (row & 7);
      gload16(Bt + gn * ldb + k0 + g * 8, &Bs[(i * 32 + wid * 8) * 64]);
    }
    __syncthreads();

#pragma unroll
    for (int kk = 0; kk < 2; ++kk) {
      bf16x8_t a[4], b[4];
#pragma unroll
      for (int m = 0; m < 4; ++m) {
        const int row = wr * 64 + m * 16 + l15;
        const int c = (kk * 4 + l4) ^ (row & 7);
        a[m] = *(const bf16x8_t*)&As[row * 64 + c * 8];
      }
#pragma unroll
      for (int n = 0; n < 4; ++n) {
        const int row = wc * 64 + n * 16 + l15;
        const int c = (kk * 4 + l4) ^ (row & 7);
        b[n] = *(const bf16x8_t*)&Bs[row * 64 + c * 8];
      }
#pragma unroll
      for (int m = 0; m < 4; ++m)
#pragma unroll
        for (int n = 0; n < 4; ++n)
          acc[m][n] = __builtin_amdgcn_mfma_f32_16x16x32_bf16(a[m], b[n], acc[m][n], 0, 0, 0);
    }
    __syncthreads();
  }

  // ---- epilogue: C/D layout col = lane&15, row = (lane>>4)*4 + j ----
  float*          Cf = (float*)Cp;
  unsigned short* Cb = (unsigned short*)Cp;
#pragma unroll
  for (int m = 0; m < 4; ++m)
#pragma unroll
    for (int n = 0; n < 4; ++n) {
      const int col = bx * 128 + wc * 64 + n * 16 + l15;
      const float bv = HAS_BIAS ? bias[col] : 0.f;
#pragma unroll
      for (int j = 0; j < 4; ++j) {
        const int row = by * 128 + wr * 64 + m * 16 + l4 * 4 + j;
        const float val = acc[m][n][j] * scale + bv;
        if (OUT_BF16) Cb[(size_t)row * ldc + col] = f2b(val);
        else          Cf[(size_t)row * ldc + col] = val;
      }
    }
}

// ---------------------------------------------------------------------------
// Fused QKV projection, XCD-swizzled. 1536 blocks; all bx of a given (z,by)
// share d%8 -> same XCD -> A-panel reuse in its private L2.
// decode: xcd=d&7, j=d>>3 (0..191), G=xcd*24+(j>>3) (0..191) -> z=G/64,
// by=G%64, bx=j&7.
// ---------------------------------------------------------------------------
__global__ __launch_bounds__(256)
void gemm_qkv(const unsigned short* __restrict__ qi,
              const unsigned short* __restrict__ ki,
              const unsigned short* __restrict__ vi,
              const unsigned short* __restrict__ Wq,
              const unsigned short* __restrict__ Wk,
              const unsigned short* __restrict__ Wv,
              const float* __restrict__ bq, const float* __restrict__ bk,
              const float* __restrict__ bv,
              unsigned short* __restrict__ oq, unsigned short* __restrict__ ok,
              unsigned short* __restrict__ ov)
{
  const int d = blockIdx.x;
  const int xcd = d & 7, j = d >> 3;
  const int G = xcd * 24 + (j >> 3);
  const int z = G >> 6;
  const int by = G & 63;
  const int bx = j & 7;
  const unsigned short* A = z == 0 ? qi : (z == 1 ? ki : vi);
  const unsigned short* B = z == 0 ? Wq : (z == 1 ? Wk : Wv);
  const float* bias = z == 0 ? bq : (z == 1 ? bk : bv);
  unsigned short* C = z == 0 ? oq : (z == 1 ? ok : ov);
  gemm_body<true, true>(A, B, bias, C, 1024, 1024, 1024, 1024, 1.f, bx, by);
}

// ---------------------------------------------------------------------------
// Scores = q k^T / 32. 544 blocks = 8 XCD chunks x 68. t = xcd*68 + j,
// bz = t/136, triangular decode within batch (bx fastest -> Q-panel reuse).
// ---------------------------------------------------------------------------
__global__ __launch_bounds__(256)
void gemm_scores(const unsigned short* __restrict__ Q,
                 const unsigned short* __restrict__ Kb, float* __restrict__ S)
{
  const int d = blockIdx.x;
  const int t = (d & 7) * 68 + (d >> 3);
  const int bz = t / 136;
  const int tri = t - bz * 136;
  int by = (int)((sqrtf(8.f * tri + 1.f) - 1.f) * 0.5f);
  while ((by + 1) * (by + 2) / 2 <= tri) ++by;
  while (by * (by + 1) / 2 > tri) --by;
  const int bx = tri - by * (by + 1) / 2;
  gemm_body<false, false>(Q + (size_t)bz * 2048 * 1024,
                          Kb + (size_t)bz * 2048 * 1024, nullptr,
                          S + (size_t)bz * 2048 * 2048,
                          1024, 1024, 1024, 2048, 0.03125f, bx, by);
}

// ---------------------------------------------------------------------------
// O = P @ V. 512 blocks, XCD-swizzled: G=xcd*8+(j>>3) -> bz=G/16, by=G%16,
// bx=j&7. Causal K-limit kEnd=(by+1)*128.
// ---------------------------------------------------------------------------
__global__ __launch_bounds__(256)
void gemm_pv(const unsigned short* __restrict__ P,
             const unsigned short* __restrict__ Vt, unsigned short* __restrict__ C)
{
  const int d = blockIdx.x;
  const int xcd = d & 7, j = d >> 3;
  const int G = xcd * 8 + (j >> 3);
  const int bz = G >> 4;
  const int by = G & 15;
  const int bx = j & 7;
  const int kEnd = (by + 1) * 128;
  gemm_body<false, true>(P + (size_t)bz * 2048 * 4096,
                         Vt + (size_t)bz * 1024 * 2048, nullptr,
                         C + (size_t)bz * 2048 * 1024,
                         kEnd, 4096, 2048, 1024, 1.f, bx, by);
}

// ---------------------------------------------------------------------------
// out = ctx @ Wo + bo -> fp32. 512 blocks, XCD-swizzled.
// ---------------------------------------------------------------------------
__global__ __launch_bounds__(256)
void gemm_out(const unsigned short* __restrict__ ctx,
              const unsigned short* __restrict__ Wo,
              const float* __restrict__ bo, float* __restrict__ out)
{
  const int d = blockIdx.x;
  const int xcd = d & 7, j = d >> 3;
  const int by = xcd * 8 + (j >> 3);
  const int bx = j & 7;
  gemm_body<true, false>(ctx, Wo, bo, out, 1024, 1024, 1024, 1024, 1.f, bx, by);
}

// ---------------------------------------------------------------------------
// 4 weight transposes fused: z selects W. [1024][1024] f32 -> bf16 transposed.
// ---------------------------------------------------------------------------
__global__ __launch_bounds__(256)
void transpose4_w(const float* __restrict__ w0, const float* __restrict__ w1,
                  const float* __restrict__ w2, const float* __restrict__ w3,
                  unsigned short* __restrict__ o0, unsigned short* __restrict__ o1,
                  unsigned short* __restrict__ o2, unsigned short* __restrict__ o3)
{
  __shared__ unsigned short t[32][34];
  const int z = blockIdx.z;
  const float* in = z == 0 ? w0 : (z == 1 ? w1 : (z == 2 ? w2 : w3));
  unsigned short* out = z == 0 ? o0 : (z == 1 ? o1 : (z == 2 ? o2 : o3));
  const int bx = blockIdx.x, by = blockIdx.y;
  const int x = threadIdx.x, y = threadIdx.y;
#pragma unroll
  for (int yy = y; yy < 32; yy += 8)
    t[yy][x] = f2b(in[(size_t)(by * 32 + yy) * 1024 + bx * 32 + x]);
  __syncthreads();
#pragma unroll
  for (int yy = y; yy < 32; yy += 8)
    out[(size_t)(bx * 32 + yy) * 1024 + by * 32 + x] = t[x][yy];
}

// ---------------------------------------------------------------------------
// vbuf [B][S][D] bf16 -> vT [B][D][S] bf16
// ---------------------------------------------------------------------------
__global__ __launch_bounds__(256)
void transpose_v(const unsigned short* __restrict__ in, unsigned short* __restrict__ out)
{
  __shared__ unsigned short t[32][34];
  const int bx = blockIdx.x;   // col tile (D)
  const int by = blockIdx.y;   // row tile (S)
  const int bz = blockIdx.z;
  const int x = threadIdx.x, y = threadIdx.y;
  const unsigned short* inb = in + (size_t)bz * 2048 * 1024;
  unsigned short* ob = out + (size_t)bz * 1024 * 2048;
#pragma unroll
  for (int yy = y; yy < 32; yy += 8)
    t[yy][x] = inb[(size_t)(by * 32 + yy) * 1024 + bx * 32 + x];
  __syncthreads();
#pragma unroll
  for (int yy = y; yy < 32; yy += 8)
    ob[(size_t)(bx * 32 + yy) * 2048 + by * 32 + x] = t[x][yy];
}

// ---------------------------------------------------------------------------
// Causal row softmax, in-place, vectorized. Poison beyond nvalid is masked
// by assignment (never arithmetic), so 0xAA / NaN bytes are harmless.
// ---------------------------------------------------------------------------
__global__ __launch_bounds__(256)
void softmax_rows(const float* __restrict__ S, unsigned short* __restrict__ P)
{
  const int row = blockIdx.x;          // 0..8191  (= b*2048 + q)
  const int q = row & 2047;
  const float* srow = S + (size_t)row * 2048;
  unsigned short* prow = P + (size_t)row * 4096;
  const int nvalid = q + 1;
  const int kend = ((q >> 7) + 1) << 7;   // multiple of 128
  const int tid = threadIdx.x;
  const int wid = tid >> 6, lane = tid & 63;
  const int base = tid * 8;

  const float4 x0 = *(const float4*)(srow + base);
  const float4 x1 = *(const float4*)(srow + base + 4);
  float v[8] = {x0.x, x0.y, x0.z, x0.w, x1.x, x1.y, x1.z, x1.w};

  float m = -1e30f;
#pragma unroll
  for (int i = 0; i < 8; ++i) {
    if (base + i >= nvalid) v[i] = -1e30f;
    m = fmaxf(m, v[i]);
  }
#pragma unroll
  for (int off = 32; off > 0; off >>= 1) m = fmaxf(m, __shfl_xor(m, off));
  __shared__ float redm[4];
  __shared__ float reds[4];
  if (lane == 0) redm[wid] = m;
  __syncthreads();
  m = fmaxf(fmaxf(redm[0], redm[1]), fmaxf(redm[2], redm[3]));

  float s = 0.f;
  float e[8];
#pragma unroll
  for (int i = 0; i < 8; ++i) {
    e[i] = (base + i < nvalid) ? __expf(v[i] - m) : 0.f;
    s += e[i];
  }
#pragma unroll
  for (int off = 32; off > 0; off >>= 1) s += __shfl_xor(s, off);
  if (lane == 0) reds[wid] = s;
  __syncthreads();
  s = reds[0] + reds[1] + reds[2] + reds[3];
  const float inv = 1.f / s;

  if (base < kend) {
    union { unsigned u[4]; uint4 v4; } pk;
#pragma unroll
    for (int i = 0; i < 4; ++i) {
      const unsigned lo = f2b(e[2 * i] * inv);
      const unsigned hi = f2b(e[2 * i + 1] * inv);
      pk.u[i] = lo | (hi << 16);
    }
    *(uint4*)(prow + base) = pk.v4;
  }
}

// ---------------------------------------------------------------------------
extern "C" void kernel_launch(void* const* d_in, const int* in_sizes, int n_in,
                              void* d_out, int out_size, void* d_ws, size_t ws_size,
                              hipStream_t stream)
{
  const float* query = (const float*)d_in[0];
  const float* key   = (const float*)d_in[1];
  const float* value = (const float*)d_in[2];
  const float* Wq    = (const float*)d_in[3];
  const float* bq    = (const float*)d_in[4];
  const float* Wk    = (const float*)d_in[5];
  const float* bk    = (const float*)d_in[6];
  const float* Wv    = (const float*)d_in[7];
  const float* bv    = (const float*)d_in[8];
  const float* Wo    = (const float*)d_in[9];
  const float* bo    = (const float*)d_in[10];
  float* out = (float*)d_out;

  char* ws = (char*)d_ws;
  const size_t MB = 1024 * 1024;
  unsigned short* Wqt  = (unsigned short*)(ws + 0 * MB);    // 2 MB each
  unsigned short* Wkt  = (unsigned short*)(ws + 2 * MB);
  unsigned short* Wvt  = (unsigned short*)(ws + 4 * MB);
  unsigned short* Wot  = (unsigned short*)(ws + 6 * MB);
  unsigned short* qbuf = (unsigned short*)(ws + 8 * MB);    // 16 MB each
  unsigned short* kbuf = (unsigned short*)(ws + 24 * MB);
  unsigned short* vbuf = (unsigned short*)(ws + 40 * MB);
  unsigned short* vT   = (unsigned short*)(ws + 56 * MB);
  float*          Sraw = (float*)(ws + 72 * MB);            // 64 MB
  // cast outputs alias Sraw (dead before gemm_scores writes it)
  unsigned short* qin  = (unsigned short*)(ws + 72 * MB);   // 16 MB each
  unsigned short* kin  = (unsigned short*)(ws + 88 * MB);
  unsigned short* vin  = (unsigned short*)(ws + 104 * MB);
  unsigned short* ctx  = (unsigned short*)(ws + 136 * MB);  // 16 MB

  // 1) cast q/k/v fp32 -> bf16
  cast3_bf16<<<dim3(4096, 1, 3), 256, 0, stream>>>(query, key, value, qin, kin, vin);

  // 2) weights -> B^T bf16 (fused x4)
  transpose4_w<<<dim3(32, 32, 4), dim3(32, 8), 0, stream>>>(
      Wq, Wk, Wv, Wo, Wqt, Wkt, Wvt, Wot);

  // 3) fused q/k/v projections (all-bf16, XCD-swizzled)
  gemm_qkv<<<1536, 256, 0, stream>>>(
      qin, kin, vin, Wqt, Wkt, Wvt, bq, bk, bv, qbuf, kbuf, vbuf);

  // 4) v -> vT [B][D][S]
  transpose_v<<<dim3(32, 64, 4), dim3(32, 8), 0, stream>>>(vbuf, vT);

  // 5) scores = q k^T / 32 (packed triangular, XCD-swizzled), fp32 out
  gemm_scores<<<544, 256, 0, stream>>>(qbuf, kbuf, Sraw);

  // 6) causal softmax, in-place P (bf16) over Sraw
  softmax_rows<<<8192, 256, 0, stream>>>(Sraw, (unsigned short*)Sraw);

  // 7) O = P @ V (causal K-limit, XCD-swizzled)
  gemm_pv<<<512, 256, 0, stream>>>((unsigned short*)Sraw, vT, ctx);

  // 8) out = ctx @ Wo + bo -> fp32 d_out
  gemm_out<<<512, 256, 0, stream>>>(ctx, Wot, bo, out);
}